// Round 1
// baseline (985.690 us; speedup 1.0000x reference)
//
#include <hip/hip_runtime.h>
#include <math.h>

#define N_NODES 100000
#define N_EDGES 1600000
#define F_IN    4
#define HID     128
#define N_CLS   5
#define N_GRAPH 256

// ---------------- degree histogram over dst (self-loops added analytically) ---------------
__global__ __launch_bounds__(256) void k_hist(const int* __restrict__ dst, int* __restrict__ deg) {
    int e = blockIdx.x * 256 + threadIdx.x;
    if (e < N_EDGES) atomicAdd(&deg[dst[e]], 1);
}

// ---------------- exclusive scan (3-pass) ---------------
__global__ __launch_bounds__(256) void k_scan1(const int* __restrict__ cnt, int* __restrict__ excl,
                                               int* __restrict__ bsum) {
    __shared__ int s[256];
    int i = blockIdx.x * 256 + threadIdx.x;
    int v = (i < N_NODES) ? cnt[i] : 0;
    s[threadIdx.x] = v;
    __syncthreads();
    for (int off = 1; off < 256; off <<= 1) {
        int t = (threadIdx.x >= off) ? s[threadIdx.x - off] : 0;
        __syncthreads();
        s[threadIdx.x] += t;
        __syncthreads();
    }
    if (i < N_NODES) excl[i] = s[threadIdx.x] - v;
    if (threadIdx.x == 255) bsum[blockIdx.x] = s[255];
}

__global__ __launch_bounds__(512) void k_scan2(int* __restrict__ bsum, int nb) {
    __shared__ int s[512];
    int v = (threadIdx.x < nb) ? bsum[threadIdx.x] : 0;
    s[threadIdx.x] = v;
    __syncthreads();
    for (int off = 1; off < 512; off <<= 1) {
        int t = (threadIdx.x >= off) ? s[threadIdx.x - off] : 0;
        __syncthreads();
        s[threadIdx.x] += t;
        __syncthreads();
    }
    if (threadIdx.x < nb) bsum[threadIdx.x] = s[threadIdx.x] - v;
}

__global__ __launch_bounds__(256) void k_scan3(int* __restrict__ excl, const int* __restrict__ bsum) {
    int i = blockIdx.x * 256 + threadIdx.x;
    if (i < N_NODES) excl[i] += bsum[blockIdx.x];
    if (i == 0) excl[N_NODES] = N_EDGES;   // total in-degree (w/o self loops) is exactly E
}

// ---------------- dinv = (deg+1)^-0.5  (the +1 is the self loop) ---------------
__global__ __launch_bounds__(256) void k_dinv(const int* __restrict__ deg, float* __restrict__ dinv) {
    int i = blockIdx.x * 256 + threadIdx.x;
    if (i < N_NODES) dinv[i] = rsqrtf((float)deg[i] + 1.0f);
}

// ---------------- CSR fill: sorted-by-dst edge list + per-edge norm coef ---------------
__global__ __launch_bounds__(256) void k_fill(const int* __restrict__ src, const int* __restrict__ dst,
                                              const int* __restrict__ rowptr, int* __restrict__ cursor,
                                              const float* __restrict__ dinv,
                                              int* __restrict__ ssort, float* __restrict__ csort) {
    int e = blockIdx.x * 256 + threadIdx.x;
    if (e < N_EDGES) {
        int d = dst[e], s = src[e];
        int ppos = rowptr[d] + atomicAdd(&cursor[d], 1);
        ssort[ppos] = s;
        csort[ppos] = dinv[s] * dinv[d];
    }
}

// ---------------- aggregate raw features x (N x 4) — Agg(x) before the layer-1 GEMM ----------
__global__ __launch_bounds__(256) void k_aggx(const float4* __restrict__ x, const int* __restrict__ rowptr,
                                              const int* __restrict__ ssort, const float* __restrict__ csort,
                                              const float* __restrict__ dinv, float4* __restrict__ out) {
    int i = blockIdx.x * 256 + threadIdx.x;
    if (i >= N_NODES) return;
    float di = dinv[i];
    float4 xv = x[i];
    float c0 = di * di;
    float ax = c0 * xv.x, ay = c0 * xv.y, az = c0 * xv.z, aw = c0 * xv.w;
    int beg = rowptr[i], end = rowptr[i + 1];
    for (int e = beg; e < end; ++e) {
        float c = csort[e];
        float4 v = x[ssort[e]];
        ax = fmaf(c, v.x, ax); ay = fmaf(c, v.y, ay);
        az = fmaf(c, v.z, az); aw = fmaf(c, v.w, aw);
    }
    out[i] = make_float4(ax, ay, az, aw);
}

// ---------------- layer-1 GEMM: (N x 4) @ (4 x 128) + bias, ReLU ---------------
__global__ __launch_bounds__(256) void k_gemm4(const float4* __restrict__ A, const float* __restrict__ W,
                                               const float* __restrict__ bias, float* __restrict__ out) {
    int idx = blockIdx.x * 256 + threadIdx.x;      // idx = i*128 + f
    int i = idx >> 7, f = idx & 127;
    float4 a = A[i];
    float v = bias[f];
    v = fmaf(a.x, W[f],           v);
    v = fmaf(a.y, W[HID + f],     v);
    v = fmaf(a.z, W[2 * HID + f], v);
    v = fmaf(a.w, W[3 * HID + f], v);
    out[idx] = fmaxf(v, 0.0f);
}

// ---------------- CSR aggregation, H=128 wide: out[i] = dinv_i^2 h[i] + sum coef_e h[src_e] ----
__global__ __launch_bounds__(256) void k_agg(const float* __restrict__ h, const int* __restrict__ rowptr,
                                             const int* __restrict__ ssort, const float* __restrict__ csort,
                                             const float* __restrict__ dinv, float* __restrict__ out) {
    int node = blockIdx.x * 2 + (threadIdx.x >> 7);
    int f = threadIdx.x & 127;
    if (node >= N_NODES) return;
    int beg = rowptr[node], end = rowptr[node + 1];
    float di = dinv[node];
    float acc = di * di * h[node * HID + f];
    int e = beg;
    for (; e + 4 <= end; e += 4) {
        int   s0 = ssort[e],     s1 = ssort[e + 1], s2 = ssort[e + 2], s3 = ssort[e + 3];
        float c0 = csort[e],     c1 = csort[e + 1], c2 = csort[e + 2], c3 = csort[e + 3];
        float v0 = h[s0 * HID + f], v1 = h[s1 * HID + f];
        float v2 = h[s2 * HID + f], v3 = h[s3 * HID + f];
        acc = fmaf(c0, v0, acc);
        acc = fmaf(c1, v1, acc);
        acc = fmaf(c2, v2, acc);
        acc = fmaf(c3, v3, acc);
    }
    for (; e < end; ++e) acc = fmaf(csort[e], h[ssort[e] * HID + f], acc);
    out[node * HID + f] = acc;
}

// ---------------- main GEMM: (N x 128) @ (128 x 128) + bias, ReLU; W fully LDS-resident -------
__device__ __forceinline__ void mac4(float a, const float4& w, float* acc) {
    acc[0] = fmaf(a, w.x, acc[0]);
    acc[1] = fmaf(a, w.y, acc[1]);
    acc[2] = fmaf(a, w.z, acc[2]);
    acc[3] = fmaf(a, w.w, acc[3]);
}

__global__ __launch_bounds__(256) void k_gemm128(const float* __restrict__ A, const float* __restrict__ W,
                                                 const float* __restrict__ bias, float* __restrict__ out) {
    __shared__ float sW[HID * HID];   // 64 KB
    __shared__ float sA[32 * HID];    // 16 KB
    int tid = threadIdx.x;
    const float4* W4p = (const float4*)W;
    float4* sW4 = (float4*)sW;
#pragma unroll
    for (int i = 0; i < 16; ++i) sW4[tid + 256 * i] = W4p[tid + 256 * i];
    const float4* A4p = (const float4*)(A + (size_t)blockIdx.x * 32 * HID);
    float4* sA4 = (float4*)sA;
#pragma unroll
    for (int i = 0; i < 4; ++i) sA4[tid + 256 * i] = A4p[tid + 256 * i];
    __syncthreads();

    int tx = tid & 31;   // col group: cols tx*4 .. tx*4+3
    int ty = tid >> 5;   // row group: rows ty*4 .. ty*4+3
    float acc[4][4];
#pragma unroll
    for (int r = 0; r < 4; ++r)
#pragma unroll
        for (int c = 0; c < 4; ++c) acc[r][c] = 0.0f;

#pragma unroll 4
    for (int k = 0; k < HID; k += 4) {
        float4 a0 = *(const float4*)&sA[(ty * 4 + 0) * HID + k];
        float4 a1 = *(const float4*)&sA[(ty * 4 + 1) * HID + k];
        float4 a2 = *(const float4*)&sA[(ty * 4 + 2) * HID + k];
        float4 a3 = *(const float4*)&sA[(ty * 4 + 3) * HID + k];
        float4 w0 = *(const float4*)&sW[(k + 0) * HID + tx * 4];
        float4 w1 = *(const float4*)&sW[(k + 1) * HID + tx * 4];
        float4 w2 = *(const float4*)&sW[(k + 2) * HID + tx * 4];
        float4 w3 = *(const float4*)&sW[(k + 3) * HID + tx * 4];
        mac4(a0.x, w0, acc[0]); mac4(a0.y, w1, acc[0]); mac4(a0.z, w2, acc[0]); mac4(a0.w, w3, acc[0]);
        mac4(a1.x, w0, acc[1]); mac4(a1.y, w1, acc[1]); mac4(a1.z, w2, acc[1]); mac4(a1.w, w3, acc[1]);
        mac4(a2.x, w0, acc[2]); mac4(a2.y, w1, acc[2]); mac4(a2.z, w2, acc[2]); mac4(a2.w, w3, acc[2]);
        mac4(a3.x, w0, acc[3]); mac4(a3.y, w1, acc[3]); mac4(a3.z, w2, acc[3]); mac4(a3.w, w3, acc[3]);
    }

    float4 bv = *(const float4*)&bias[tx * 4];
    int row0 = blockIdx.x * 32 + ty * 4;
#pragma unroll
    for (int r = 0; r < 4; ++r) {
        float4 o;
        o.x = fmaxf(acc[r][0] + bv.x, 0.0f);
        o.y = fmaxf(acc[r][1] + bv.y, 0.0f);
        o.z = fmaxf(acc[r][2] + bv.z, 0.0f);
        o.w = fmaxf(acc[r][3] + bv.w, 0.0f);
        *(float4*)&out[(size_t)(row0 + r) * HID + tx * 4] = o;
    }
}

// ---------------- mean pool per graph (batch is sorted) ---------------
__global__ __launch_bounds__(128) void k_pool(const float* __restrict__ h, const int* __restrict__ batch,
                                              float* __restrict__ pooled) {
    int g = blockIdx.x, f = threadIdx.x;
    int lo = 0, hi = N_NODES;
    while (lo < hi) { int m = (lo + hi) >> 1; if (batch[m] < g) lo = m + 1; else hi = m; }
    int beg = lo;
    hi = N_NODES;
    while (lo < hi) { int m = (lo + hi) >> 1; if (batch[m] < g + 1) lo = m + 1; else hi = m; }
    int end = lo;
    float acc = 0.0f;
    for (int i = beg; i < end; ++i) acc += h[i * HID + f];
    pooled[g * HID + f] = acc / fmaxf((float)(end - beg), 1.0f);
}

// ---------------- head: sigmoid(pooled @ Wl + bl) ---------------
__global__ __launch_bounds__(256) void k_head(const float* __restrict__ pooled, const float* __restrict__ Wl,
                                              const float* __restrict__ bl, float* __restrict__ out) {
    int idx = blockIdx.x * 256 + threadIdx.x;
    if (idx >= N_GRAPH * N_CLS) return;
    int g = idx / N_CLS, c = idx % N_CLS;
    float acc = bl[c];
    for (int f = 0; f < HID; ++f) acc = fmaf(pooled[g * HID + f], Wl[f * N_CLS + c], acc);
    out[idx] = 1.0f / (1.0f + expf(-acc));
}

extern "C" void kernel_launch(void* const* d_in, const int* in_sizes, int n_in,
                              void* d_out, int out_size, void* d_ws, size_t ws_size,
                              hipStream_t stream) {
    const float* x     = (const float*)d_in[0];
    const int*   ei    = (const int*)d_in[1];
    const int*   batch = (const int*)d_in[2];
    const float* W1 = (const float*)d_in[3];  const float* b1 = (const float*)d_in[4];
    const float* W2 = (const float*)d_in[5];  const float* b2 = (const float*)d_in[6];
    const float* W3 = (const float*)d_in[7];  const float* b3 = (const float*)d_in[8];
    const float* W4 = (const float*)d_in[9];  const float* b4 = (const float*)d_in[10];
    const float* Wl = (const float*)d_in[11]; const float* bl = (const float*)d_in[12];
    float* out = (float*)d_out;

    char* p = (char*)d_ws;
    auto alloc = [&](size_t bytes) { char* r = p; p += (bytes + 255) & ~(size_t)255; return (void*)r; };
    int*   deg    = (int*)  alloc((size_t)N_NODES * 4);
    int*   rowptr = (int*)  alloc((size_t)(N_NODES + 1) * 4);
    int*   cursor = (int*)  alloc((size_t)N_NODES * 4);
    int*   bsum   = (int*)  alloc(512 * 4);
    float* dinv   = (float*)alloc((size_t)N_NODES * 4);
    int*   ssort  = (int*)  alloc((size_t)N_EDGES * 4);
    float* csort  = (float*)alloc((size_t)N_EDGES * 4);
    float* xagg   = (float*)alloc((size_t)N_NODES * F_IN * 4);
    float* h0     = (float*)alloc((size_t)N_NODES * HID * 4);
    float* h1     = (float*)alloc((size_t)N_NODES * HID * 4);
    float* pooled = (float*)alloc((size_t)N_GRAPH * HID * 4);

    const int* srcv = ei;              // edge_index[0]
    const int* dstv = ei + N_EDGES;    // edge_index[1]

    hipMemsetAsync(deg, 0, (size_t)N_NODES * 4, stream);
    hipMemsetAsync(cursor, 0, (size_t)N_NODES * 4, stream);

    const int nb = (N_NODES + 255) / 256;   // 391

    k_hist <<<N_EDGES / 256, 256, 0, stream>>>(dstv, deg);
    k_scan1<<<nb, 256, 0, stream>>>(deg, rowptr, bsum);
    k_scan2<<<1, 512, 0, stream>>>(bsum, nb);
    k_scan3<<<nb, 256, 0, stream>>>(rowptr, bsum);
    k_dinv <<<nb, 256, 0, stream>>>(deg, dinv);
    k_fill <<<N_EDGES / 256, 256, 0, stream>>>(srcv, dstv, rowptr, cursor, dinv, ssort, csort);

    // layer 1: Agg(x) @ W1  (aggregate the 4-wide features, then expand to 128)
    k_aggx <<<nb, 256, 0, stream>>>((const float4*)x, rowptr, ssort, csort, dinv, (float4*)xagg);
    k_gemm4<<<(N_NODES * HID) / 256, 256, 0, stream>>>((const float4*)xagg, W1, b1, h0);

    // layers 2..4: Agg(h) @ W  (+bias, ReLU fused in GEMM epilogue)
    k_agg    <<<N_NODES / 2, 256, 0, stream>>>(h0, rowptr, ssort, csort, dinv, h1);
    k_gemm128<<<N_NODES / 32, 256, 0, stream>>>(h1, W2, b2, h0);
    k_agg    <<<N_NODES / 2, 256, 0, stream>>>(h0, rowptr, ssort, csort, dinv, h1);
    k_gemm128<<<N_NODES / 32, 256, 0, stream>>>(h1, W3, b3, h0);
    k_agg    <<<N_NODES / 2, 256, 0, stream>>>(h0, rowptr, ssort, csort, dinv, h1);
    k_gemm128<<<N_NODES / 32, 256, 0, stream>>>(h1, W4, b4, h0);

    k_pool<<<N_GRAPH, 128, 0, stream>>>(h0, batch, pooled);
    k_head<<<(N_GRAPH * N_CLS + 255) / 256, 256, 0, stream>>>(pooled, Wl, bl, out);
}

// Round 2
// 768.212 us; speedup vs baseline: 1.2831x; 1.2831x over previous
//
#include <hip/hip_runtime.h>
#include <math.h>

#define N_NODES 100000
#define N_EDGES 1600000
#define F_IN    4
#define HID     128
#define N_CLS   5
#define N_GRAPH 256

typedef _Float16 f16;
typedef _Float16 f16x2 __attribute__((ext_vector_type(2)));
typedef _Float16 f16x4 __attribute__((ext_vector_type(4)));
typedef _Float16 f16x8 __attribute__((ext_vector_type(8)));

// ---------------- degree histogram over dst (self-loops added analytically) ---------------
__global__ __launch_bounds__(256) void k_hist(const int* __restrict__ dst, int* __restrict__ deg) {
    int e = blockIdx.x * 256 + threadIdx.x;
    if (e < N_EDGES) atomicAdd(&deg[dst[e]], 1);
}

// ---------------- exclusive scan (3-pass) ---------------
__global__ __launch_bounds__(256) void k_scan1(const int* __restrict__ cnt, int* __restrict__ excl,
                                               int* __restrict__ bsum) {
    __shared__ int s[256];
    int i = blockIdx.x * 256 + threadIdx.x;
    int v = (i < N_NODES) ? cnt[i] : 0;
    s[threadIdx.x] = v;
    __syncthreads();
    for (int off = 1; off < 256; off <<= 1) {
        int t = (threadIdx.x >= off) ? s[threadIdx.x - off] : 0;
        __syncthreads();
        s[threadIdx.x] += t;
        __syncthreads();
    }
    if (i < N_NODES) excl[i] = s[threadIdx.x] - v;
    if (threadIdx.x == 255) bsum[blockIdx.x] = s[255];
}

__global__ __launch_bounds__(512) void k_scan2(int* __restrict__ bsum, int nb) {
    __shared__ int s[512];
    int v = (threadIdx.x < nb) ? bsum[threadIdx.x] : 0;
    s[threadIdx.x] = v;
    __syncthreads();
    for (int off = 1; off < 512; off <<= 1) {
        int t = (threadIdx.x >= off) ? s[threadIdx.x - off] : 0;
        __syncthreads();
        s[threadIdx.x] += t;
        __syncthreads();
    }
    if (threadIdx.x < nb) bsum[threadIdx.x] = s[threadIdx.x] - v;
}

__global__ __launch_bounds__(256) void k_scan3(int* __restrict__ excl, const int* __restrict__ bsum) {
    int i = blockIdx.x * 256 + threadIdx.x;
    if (i < N_NODES) excl[i] += bsum[blockIdx.x];
    if (i == 0) excl[N_NODES] = N_EDGES;   // total in-degree (w/o self loops) is exactly E
}

// ---------------- dinv = (deg+1)^-0.5  (the +1 is the self loop) ---------------
__global__ __launch_bounds__(256) void k_dinv(const int* __restrict__ deg, float* __restrict__ dinv) {
    int i = blockIdx.x * 256 + threadIdx.x;
    if (i < N_NODES) dinv[i] = rsqrtf((float)deg[i] + 1.0f);
}

// ---------------- CSR fill: (src, coef) packed as int2 — one 8B scattered write per edge -----
__global__ __launch_bounds__(256) void k_fill(const int* __restrict__ src, const int* __restrict__ dst,
                                              const int* __restrict__ rowptr, int* __restrict__ cursor,
                                              const float* __restrict__ dinv,
                                              int2* __restrict__ edges) {
    int e = blockIdx.x * 256 + threadIdx.x;
    if (e < N_EDGES) {
        int d = dst[e], s = src[e];
        int ppos = rowptr[d] + atomicAdd(&cursor[d], 1);
        float c = dinv[s] * dinv[d];
        edges[ppos] = make_int2(s, __float_as_int(c));
    }
}

// ---------------- aggregate raw features x (N x 4) — Agg(x) before the layer-1 GEMM ----------
__global__ __launch_bounds__(256) void k_aggx(const float4* __restrict__ x, const int* __restrict__ rowptr,
                                              const int2* __restrict__ edges,
                                              const float* __restrict__ dinv, float4* __restrict__ out) {
    int i = blockIdx.x * 256 + threadIdx.x;
    if (i >= N_NODES) return;
    float di = dinv[i];
    float4 xv = x[i];
    float c0 = di * di;
    float ax = c0 * xv.x, ay = c0 * xv.y, az = c0 * xv.z, aw = c0 * xv.w;
    int beg = rowptr[i], end = rowptr[i + 1];
    for (int e = beg; e < end; ++e) {
        int2 m = edges[e];
        float c = __int_as_float(m.y);
        float4 v = x[m.x];
        ax = fmaf(c, v.x, ax); ay = fmaf(c, v.y, ay);
        az = fmaf(c, v.z, az); aw = fmaf(c, v.w, aw);
    }
    out[i] = make_float4(ax, ay, az, aw);
}

// ---------------- layer-1 GEMM: (N x 4) @ (4 x 128) + bias, ReLU, fp16 out ---------------
__global__ __launch_bounds__(256) void k_gemm4(const float4* __restrict__ A, const float* __restrict__ W,
                                               const float* __restrict__ bias, f16x2* __restrict__ out) {
    int idx = blockIdx.x * 256 + threadIdx.x;      // idx = i*64 + fpair
    int i = idx >> 6, fp = (idx & 63) * 2;
    float4 a = A[i];
    float v0 = bias[fp];
    v0 = fmaf(a.x, W[fp],           v0);
    v0 = fmaf(a.y, W[HID + fp],     v0);
    v0 = fmaf(a.z, W[2 * HID + fp], v0);
    v0 = fmaf(a.w, W[3 * HID + fp], v0);
    float v1 = bias[fp + 1];
    v1 = fmaf(a.x, W[fp + 1],           v1);
    v1 = fmaf(a.y, W[HID + fp + 1],     v1);
    v1 = fmaf(a.z, W[2 * HID + fp + 1], v1);
    v1 = fmaf(a.w, W[3 * HID + fp + 1], v1);
    f16x2 o;
    o.x = (f16)fmaxf(v0, 0.0f);
    o.y = (f16)fmaxf(v1, 0.0f);
    out[idx] = o;
}

// ---------------- CSR aggregation, fp16 payload: one wave per node, half2 per lane -----------
__global__ __launch_bounds__(256) void k_agg(const f16x2* __restrict__ h, const int* __restrict__ rowptr,
                                             const int2* __restrict__ edges,
                                             const float* __restrict__ dinv, f16x2* __restrict__ out) {
    int node = blockIdx.x * 4 + (threadIdx.x >> 6);
    if (node >= N_NODES) return;
    int lane = threadIdx.x & 63;
    int beg = rowptr[node], end = rowptr[node + 1];
    float di = dinv[node];
    f16x2 self = h[node * 64 + lane];
    float c0 = di * di;
    float accx = c0 * (float)self.x;
    float accy = c0 * (float)self.y;
    int e = beg;
    for (; e + 8 <= end; e += 8) {
        int2 m0 = edges[e + 0], m1 = edges[e + 1], m2 = edges[e + 2], m3 = edges[e + 3];
        int2 m4 = edges[e + 4], m5 = edges[e + 5], m6 = edges[e + 6], m7 = edges[e + 7];
        f16x2 v0 = h[m0.x * 64 + lane], v1 = h[m1.x * 64 + lane];
        f16x2 v2 = h[m2.x * 64 + lane], v3 = h[m3.x * 64 + lane];
        f16x2 v4 = h[m4.x * 64 + lane], v5 = h[m5.x * 64 + lane];
        f16x2 v6 = h[m6.x * 64 + lane], v7 = h[m7.x * 64 + lane];
        accx = fmaf(__int_as_float(m0.y), (float)v0.x, accx);
        accy = fmaf(__int_as_float(m0.y), (float)v0.y, accy);
        accx = fmaf(__int_as_float(m1.y), (float)v1.x, accx);
        accy = fmaf(__int_as_float(m1.y), (float)v1.y, accy);
        accx = fmaf(__int_as_float(m2.y), (float)v2.x, accx);
        accy = fmaf(__int_as_float(m2.y), (float)v2.y, accy);
        accx = fmaf(__int_as_float(m3.y), (float)v3.x, accx);
        accy = fmaf(__int_as_float(m3.y), (float)v3.y, accy);
        accx = fmaf(__int_as_float(m4.y), (float)v4.x, accx);
        accy = fmaf(__int_as_float(m4.y), (float)v4.y, accy);
        accx = fmaf(__int_as_float(m5.y), (float)v5.x, accx);
        accy = fmaf(__int_as_float(m5.y), (float)v5.y, accy);
        accx = fmaf(__int_as_float(m6.y), (float)v6.x, accx);
        accy = fmaf(__int_as_float(m6.y), (float)v6.y, accy);
        accx = fmaf(__int_as_float(m7.y), (float)v7.x, accx);
        accy = fmaf(__int_as_float(m7.y), (float)v7.y, accy);
    }
    for (; e < end; ++e) {
        int2 m = edges[e];
        f16x2 v = h[m.x * 64 + lane];
        float c = __int_as_float(m.y);
        accx = fmaf(c, (float)v.x, accx);
        accy = fmaf(c, (float)v.y, accy);
    }
    f16x2 o;
    o.x = (f16)accx;
    o.y = (f16)accy;
    out[node * 64 + lane] = o;
}

// ---------------- main GEMM: (N x 128 fp16) @ (128 x 128 fp32) + bias, ReLU, fp16 out --------
__device__ __forceinline__ void mac4(float a, const float4& w, float* acc) {
    acc[0] = fmaf(a, w.x, acc[0]);
    acc[1] = fmaf(a, w.y, acc[1]);
    acc[2] = fmaf(a, w.z, acc[2]);
    acc[3] = fmaf(a, w.w, acc[3]);
}

__global__ __launch_bounds__(256) void k_gemm128(const f16* __restrict__ A, const float* __restrict__ W,
                                                 const float* __restrict__ bias, f16* __restrict__ out) {
    __shared__ float sW[HID * HID];   // 64 KB
    __shared__ float sA[32 * HID];    // 16 KB
    int tid = threadIdx.x;
    const float4* W4p = (const float4*)W;
    float4* sW4 = (float4*)sW;
#pragma unroll
    for (int i = 0; i < 16; ++i) sW4[tid + 256 * i] = W4p[tid + 256 * i];
    // A tile: 32 rows x 128 halves = 4096 halves; convert to fp32 in LDS
    const f16x8* A8 = (const f16x8*)(A + (size_t)blockIdx.x * 32 * HID);
#pragma unroll
    for (int i = 0; i < 2; ++i) {
        f16x8 v = A8[tid + 256 * i];
        int base = (tid + 256 * i) * 8;
#pragma unroll
        for (int j = 0; j < 8; ++j) sA[base + j] = (float)v[j];
    }
    __syncthreads();

    int tx = tid & 31;   // col group: cols tx*4 .. tx*4+3
    int ty = tid >> 5;   // row group: rows ty*4 .. ty*4+3
    float acc[4][4];
#pragma unroll
    for (int r = 0; r < 4; ++r)
#pragma unroll
        for (int c = 0; c < 4; ++c) acc[r][c] = 0.0f;

#pragma unroll 4
    for (int k = 0; k < HID; k += 4) {
        float4 a0 = *(const float4*)&sA[(ty * 4 + 0) * HID + k];
        float4 a1 = *(const float4*)&sA[(ty * 4 + 1) * HID + k];
        float4 a2 = *(const float4*)&sA[(ty * 4 + 2) * HID + k];
        float4 a3 = *(const float4*)&sA[(ty * 4 + 3) * HID + k];
        float4 w0 = *(const float4*)&sW[(k + 0) * HID + tx * 4];
        float4 w1 = *(const float4*)&sW[(k + 1) * HID + tx * 4];
        float4 w2 = *(const float4*)&sW[(k + 2) * HID + tx * 4];
        float4 w3 = *(const float4*)&sW[(k + 3) * HID + tx * 4];
        mac4(a0.x, w0, acc[0]); mac4(a0.y, w1, acc[0]); mac4(a0.z, w2, acc[0]); mac4(a0.w, w3, acc[0]);
        mac4(a1.x, w0, acc[1]); mac4(a1.y, w1, acc[1]); mac4(a1.z, w2, acc[1]); mac4(a1.w, w3, acc[1]);
        mac4(a2.x, w0, acc[2]); mac4(a2.y, w1, acc[2]); mac4(a2.z, w2, acc[2]); mac4(a2.w, w3, acc[2]);
        mac4(a3.x, w0, acc[3]); mac4(a3.y, w1, acc[3]); mac4(a3.z, w2, acc[3]); mac4(a3.w, w3, acc[3]);
    }

    float4 bv = *(const float4*)&bias[tx * 4];
    int row0 = blockIdx.x * 32 + ty * 4;
#pragma unroll
    for (int r = 0; r < 4; ++r) {
        f16x4 o;
        o.x = (f16)fmaxf(acc[r][0] + bv.x, 0.0f);
        o.y = (f16)fmaxf(acc[r][1] + bv.y, 0.0f);
        o.z = (f16)fmaxf(acc[r][2] + bv.z, 0.0f);
        o.w = (f16)fmaxf(acc[r][3] + bv.w, 0.0f);
        *(f16x4*)&out[(size_t)(row0 + r) * HID + tx * 4] = o;
    }
}

// ---------------- mean pool per graph (batch is sorted), fp16 in / fp32 out ---------------
__global__ __launch_bounds__(128) void k_pool(const f16* __restrict__ h, const int* __restrict__ batch,
                                              float* __restrict__ pooled) {
    int g = blockIdx.x, f = threadIdx.x;
    int lo = 0, hi = N_NODES;
    while (lo < hi) { int m = (lo + hi) >> 1; if (batch[m] < g) lo = m + 1; else hi = m; }
    int beg = lo;
    hi = N_NODES;
    while (lo < hi) { int m = (lo + hi) >> 1; if (batch[m] < g + 1) lo = m + 1; else hi = m; }
    int end = lo;
    float acc = 0.0f;
    for (int i = beg; i < end; ++i) acc += (float)h[i * HID + f];
    pooled[g * HID + f] = acc / fmaxf((float)(end - beg), 1.0f);
}

// ---------------- head: sigmoid(pooled @ Wl + bl) ---------------
__global__ __launch_bounds__(256) void k_head(const float* __restrict__ pooled, const float* __restrict__ Wl,
                                              const float* __restrict__ bl, float* __restrict__ out) {
    int idx = blockIdx.x * 256 + threadIdx.x;
    if (idx >= N_GRAPH * N_CLS) return;
    int g = idx / N_CLS, c = idx % N_CLS;
    float acc = bl[c];
    for (int f = 0; f < HID; ++f) acc = fmaf(pooled[g * HID + f], Wl[f * N_CLS + c], acc);
    out[idx] = 1.0f / (1.0f + expf(-acc));
}

extern "C" void kernel_launch(void* const* d_in, const int* in_sizes, int n_in,
                              void* d_out, int out_size, void* d_ws, size_t ws_size,
                              hipStream_t stream) {
    const float* x     = (const float*)d_in[0];
    const int*   ei    = (const int*)d_in[1];
    const int*   batch = (const int*)d_in[2];
    const float* W1 = (const float*)d_in[3];  const float* b1 = (const float*)d_in[4];
    const float* W2 = (const float*)d_in[5];  const float* b2 = (const float*)d_in[6];
    const float* W3 = (const float*)d_in[7];  const float* b3 = (const float*)d_in[8];
    const float* W4 = (const float*)d_in[9];  const float* b4 = (const float*)d_in[10];
    const float* Wl = (const float*)d_in[11]; const float* bl = (const float*)d_in[12];
    float* out = (float*)d_out;

    char* p = (char*)d_ws;
    auto alloc = [&](size_t bytes) { char* r = p; p += (bytes + 255) & ~(size_t)255; return (void*)r; };
    int*   deg    = (int*)  alloc((size_t)N_NODES * 4);
    int*   rowptr = (int*)  alloc((size_t)(N_NODES + 1) * 4);
    int*   cursor = (int*)  alloc((size_t)N_NODES * 4);
    int*   bsum   = (int*)  alloc(512 * 4);
    float* dinv   = (float*)alloc((size_t)N_NODES * 4);
    int2*  edges  = (int2*) alloc((size_t)N_EDGES * 8);
    float* xagg   = (float*)alloc((size_t)N_NODES * F_IN * 4);
    f16*   h0     = (f16*)  alloc((size_t)N_NODES * HID * 2);
    f16*   h1     = (f16*)  alloc((size_t)N_NODES * HID * 2);
    float* pooled = (float*)alloc((size_t)N_GRAPH * HID * 4);

    const int* srcv = ei;              // edge_index[0]
    const int* dstv = ei + N_EDGES;    // edge_index[1]

    hipMemsetAsync(deg, 0, (size_t)N_NODES * 4, stream);
    hipMemsetAsync(cursor, 0, (size_t)N_NODES * 4, stream);

    const int nb = (N_NODES + 255) / 256;   // 391

    k_hist <<<N_EDGES / 256, 256, 0, stream>>>(dstv, deg);
    k_scan1<<<nb, 256, 0, stream>>>(deg, rowptr, bsum);
    k_scan2<<<1, 512, 0, stream>>>(bsum, nb);
    k_scan3<<<nb, 256, 0, stream>>>(rowptr, bsum);
    k_dinv <<<nb, 256, 0, stream>>>(deg, dinv);
    k_fill <<<N_EDGES / 256, 256, 0, stream>>>(srcv, dstv, rowptr, cursor, dinv, edges);

    // layer 1: Agg(x) @ W1  (aggregate the 4-wide features, then expand to 128)
    k_aggx <<<nb, 256, 0, stream>>>((const float4*)x, rowptr, edges, dinv, (float4*)xagg);
    k_gemm4<<<(N_NODES * 64) / 256, 256, 0, stream>>>((const float4*)xagg, W1, b1, (f16x2*)h0);

    // layers 2..4: Agg(h) @ W  (+bias, ReLU fused in GEMM epilogue)
    k_agg    <<<N_NODES / 4, 256, 0, stream>>>((const f16x2*)h0, rowptr, edges, dinv, (f16x2*)h1);
    k_gemm128<<<N_NODES / 32, 256, 0, stream>>>(h1, W2, b2, h0);
    k_agg    <<<N_NODES / 4, 256, 0, stream>>>((const f16x2*)h0, rowptr, edges, dinv, (f16x2*)h1);
    k_gemm128<<<N_NODES / 32, 256, 0, stream>>>(h1, W3, b3, h0);
    k_agg    <<<N_NODES / 4, 256, 0, stream>>>((const f16x2*)h0, rowptr, edges, dinv, (f16x2*)h1);
    k_gemm128<<<N_NODES / 32, 256, 0, stream>>>(h1, W4, b4, h0);

    k_pool<<<N_GRAPH, 128, 0, stream>>>(h0, batch, pooled);
    k_head<<<(N_GRAPH * N_CLS + 255) / 256, 256, 0, stream>>>(pooled, Wl, bl, out);
}

// Round 3
// 668.242 us; speedup vs baseline: 1.4750x; 1.1496x over previous
//
#include <hip/hip_runtime.h>
#include <math.h>

#define N_NODES 100000
#define N_EDGES 1600000
#define F_IN    4
#define HID     128
#define N_CLS   5
#define N_GRAPH 256
#define POOL_SEG 8

typedef _Float16 f16;
typedef _Float16 f16x2 __attribute__((ext_vector_type(2)));
typedef _Float16 f16x4 __attribute__((ext_vector_type(4)));
typedef _Float16 f16x8 __attribute__((ext_vector_type(8)));

// ---------------- degree histogram over dst (self-loops added analytically) ---------------
__global__ __launch_bounds__(256) void k_hist(const int* __restrict__ dst, int* __restrict__ deg) {
    int e = blockIdx.x * 256 + threadIdx.x;
    if (e < N_EDGES) atomicAdd(&deg[dst[e]], 1);
}

// ---------------- exclusive scan (3-pass) ---------------
__global__ __launch_bounds__(256) void k_scan1(const int* __restrict__ cnt, int* __restrict__ excl,
                                               int* __restrict__ bsum) {
    __shared__ int s[256];
    int i = blockIdx.x * 256 + threadIdx.x;
    int v = (i < N_NODES) ? cnt[i] : 0;
    s[threadIdx.x] = v;
    __syncthreads();
    for (int off = 1; off < 256; off <<= 1) {
        int t = (threadIdx.x >= off) ? s[threadIdx.x - off] : 0;
        __syncthreads();
        s[threadIdx.x] += t;
        __syncthreads();
    }
    if (i < N_NODES) excl[i] = s[threadIdx.x] - v;
    if (threadIdx.x == 255) bsum[blockIdx.x] = s[255];
}

__global__ __launch_bounds__(512) void k_scan2(int* __restrict__ bsum, int nb) {
    __shared__ int s[512];
    int v = (threadIdx.x < nb) ? bsum[threadIdx.x] : 0;
    s[threadIdx.x] = v;
    __syncthreads();
    for (int off = 1; off < 512; off <<= 1) {
        int t = (threadIdx.x >= off) ? s[threadIdx.x - off] : 0;
        __syncthreads();
        s[threadIdx.x] += t;
        __syncthreads();
    }
    if (threadIdx.x < nb) bsum[threadIdx.x] = s[threadIdx.x] - v;
}

__global__ __launch_bounds__(256) void k_scan3(int* __restrict__ excl, const int* __restrict__ bsum) {
    int i = blockIdx.x * 256 + threadIdx.x;
    if (i < N_NODES) excl[i] += bsum[blockIdx.x];
    if (i == 0) excl[N_NODES] = N_EDGES;   // total in-degree (w/o self loops) is exactly E
}

// ---------------- dinv = (deg+1)^-0.5  (the +1 is the self loop) ---------------
__global__ __launch_bounds__(256) void k_dinv(const int* __restrict__ deg, float* __restrict__ dinv) {
    int i = blockIdx.x * 256 + threadIdx.x;
    if (i < N_NODES) dinv[i] = rsqrtf((float)deg[i] + 1.0f);
}

// ---------------- CSR fill: (src, coef) packed as int2 — one 8B scattered write per edge -----
__global__ __launch_bounds__(256) void k_fill(const int* __restrict__ src, const int* __restrict__ dst,
                                              const int* __restrict__ rowptr, int* __restrict__ cursor,
                                              const float* __restrict__ dinv,
                                              int2* __restrict__ edges) {
    int e = blockIdx.x * 256 + threadIdx.x;
    if (e < N_EDGES) {
        int d = dst[e], s = src[e];
        int ppos = rowptr[d] + atomicAdd(&cursor[d], 1);
        float c = dinv[s] * dinv[d];
        edges[ppos] = make_int2(s, __float_as_int(c));
    }
}

// ---------------- aggregate raw features x (N x 4) — Agg(x) before the layer-1 GEMM ----------
__global__ __launch_bounds__(256) void k_aggx(const float4* __restrict__ x, const int* __restrict__ rowptr,
                                              const int2* __restrict__ edges,
                                              const float* __restrict__ dinv, float4* __restrict__ out) {
    int i = blockIdx.x * 256 + threadIdx.x;
    if (i >= N_NODES) return;
    float di = dinv[i];
    float4 xv = x[i];
    float c0 = di * di;
    float ax = c0 * xv.x, ay = c0 * xv.y, az = c0 * xv.z, aw = c0 * xv.w;
    int beg = rowptr[i], end = rowptr[i + 1];
    for (int e = beg; e < end; ++e) {
        int2 m = edges[e];
        float c = __int_as_float(m.y);
        float4 v = x[m.x];
        ax = fmaf(c, v.x, ax); ay = fmaf(c, v.y, ay);
        az = fmaf(c, v.z, az); aw = fmaf(c, v.w, aw);
    }
    out[i] = make_float4(ax, ay, az, aw);
}

// ---------------- layer-1 GEMM: (N x 4) @ (4 x 128) + bias, ReLU, fp16 out ---------------
__global__ __launch_bounds__(256) void k_gemm4(const float4* __restrict__ A, const float* __restrict__ W,
                                               const float* __restrict__ bias, f16x2* __restrict__ out) {
    int idx = blockIdx.x * 256 + threadIdx.x;      // idx = i*64 + fpair
    int i = idx >> 6, fp = (idx & 63) * 2;
    float4 a = A[i];
    float v0 = bias[fp];
    v0 = fmaf(a.x, W[fp],           v0);
    v0 = fmaf(a.y, W[HID + fp],     v0);
    v0 = fmaf(a.z, W[2 * HID + fp], v0);
    v0 = fmaf(a.w, W[3 * HID + fp], v0);
    float v1 = bias[fp + 1];
    v1 = fmaf(a.x, W[fp + 1],           v1);
    v1 = fmaf(a.y, W[HID + fp + 1],     v1);
    v1 = fmaf(a.z, W[2 * HID + fp + 1], v1);
    v1 = fmaf(a.w, W[3 * HID + fp + 1], v1);
    f16x2 o;
    o.x = (f16)fmaxf(v0, 0.0f);
    o.y = (f16)fmaxf(v1, 0.0f);
    out[idx] = o;
}

// ---------------- CSR aggregation, fp16 payload: one wave per node, half2 per lane -----------
__global__ __launch_bounds__(256) void k_agg(const f16x2* __restrict__ h, const int* __restrict__ rowptr,
                                             const int2* __restrict__ edges,
                                             const float* __restrict__ dinv, f16x2* __restrict__ out) {
    int node = blockIdx.x * 4 + (threadIdx.x >> 6);
    if (node >= N_NODES) return;
    int lane = threadIdx.x & 63;
    int beg = rowptr[node], end = rowptr[node + 1];
    float di = dinv[node];
    f16x2 self = h[node * 64 + lane];
    float c0 = di * di;
    float accx = c0 * (float)self.x;
    float accy = c0 * (float)self.y;
    int e = beg;
    for (; e + 8 <= end; e += 8) {
        int2 m0 = edges[e + 0], m1 = edges[e + 1], m2 = edges[e + 2], m3 = edges[e + 3];
        int2 m4 = edges[e + 4], m5 = edges[e + 5], m6 = edges[e + 6], m7 = edges[e + 7];
        f16x2 v0 = h[m0.x * 64 + lane], v1 = h[m1.x * 64 + lane];
        f16x2 v2 = h[m2.x * 64 + lane], v3 = h[m3.x * 64 + lane];
        f16x2 v4 = h[m4.x * 64 + lane], v5 = h[m5.x * 64 + lane];
        f16x2 v6 = h[m6.x * 64 + lane], v7 = h[m7.x * 64 + lane];
        accx = fmaf(__int_as_float(m0.y), (float)v0.x, accx);
        accy = fmaf(__int_as_float(m0.y), (float)v0.y, accy);
        accx = fmaf(__int_as_float(m1.y), (float)v1.x, accx);
        accy = fmaf(__int_as_float(m1.y), (float)v1.y, accy);
        accx = fmaf(__int_as_float(m2.y), (float)v2.x, accx);
        accy = fmaf(__int_as_float(m2.y), (float)v2.y, accy);
        accx = fmaf(__int_as_float(m3.y), (float)v3.x, accx);
        accy = fmaf(__int_as_float(m3.y), (float)v3.y, accy);
        accx = fmaf(__int_as_float(m4.y), (float)v4.x, accx);
        accy = fmaf(__int_as_float(m4.y), (float)v4.y, accy);
        accx = fmaf(__int_as_float(m5.y), (float)v5.x, accx);
        accy = fmaf(__int_as_float(m5.y), (float)v5.y, accy);
        accx = fmaf(__int_as_float(m6.y), (float)v6.x, accx);
        accy = fmaf(__int_as_float(m6.y), (float)v6.y, accy);
        accx = fmaf(__int_as_float(m7.y), (float)v7.x, accx);
        accy = fmaf(__int_as_float(m7.y), (float)v7.y, accy);
    }
    for (; e < end; ++e) {
        int2 m = edges[e];
        f16x2 v = h[m.x * 64 + lane];
        float c = __int_as_float(m.y);
        accx = fmaf(c, (float)v.x, accx);
        accy = fmaf(c, (float)v.y, accy);
    }
    f16x2 o;
    o.x = (f16)accx;
    o.y = (f16)accy;
    out[node * 64 + lane] = o;
}

// ---------------- main GEMM: (N x 128 fp16) @ (128 x 128 fp32) + bias, ReLU, fp16 out --------
__device__ __forceinline__ void mac4(float a, const float4& w, float* acc) {
    acc[0] = fmaf(a, w.x, acc[0]);
    acc[1] = fmaf(a, w.y, acc[1]);
    acc[2] = fmaf(a, w.z, acc[2]);
    acc[3] = fmaf(a, w.w, acc[3]);
}

__global__ __launch_bounds__(256) void k_gemm128(const f16* __restrict__ A, const float* __restrict__ W,
                                                 const float* __restrict__ bias, f16* __restrict__ out) {
    __shared__ float sW[HID * HID];   // 64 KB
    __shared__ float sA[32 * HID];    // 16 KB
    int tid = threadIdx.x;
    const float4* W4p = (const float4*)W;
    float4* sW4 = (float4*)sW;
#pragma unroll
    for (int i = 0; i < 16; ++i) sW4[tid + 256 * i] = W4p[tid + 256 * i];
    // A tile: 32 rows x 128 halves = 4096 halves; convert to fp32 in LDS
    const f16x8* A8 = (const f16x8*)(A + (size_t)blockIdx.x * 32 * HID);
#pragma unroll
    for (int i = 0; i < 2; ++i) {
        f16x8 v = A8[tid + 256 * i];
        int base = (tid + 256 * i) * 8;
#pragma unroll
        for (int j = 0; j < 8; ++j) sA[base + j] = (float)v[j];
    }
    __syncthreads();

    int tx = tid & 31;   // col group: cols tx*4 .. tx*4+3
    int ty = tid >> 5;   // row group: rows ty*4 .. ty*4+3
    float acc[4][4];
#pragma unroll
    for (int r = 0; r < 4; ++r)
#pragma unroll
        for (int c = 0; c < 4; ++c) acc[r][c] = 0.0f;

#pragma unroll 4
    for (int k = 0; k < HID; k += 4) {
        float4 a0 = *(const float4*)&sA[(ty * 4 + 0) * HID + k];
        float4 a1 = *(const float4*)&sA[(ty * 4 + 1) * HID + k];
        float4 a2 = *(const float4*)&sA[(ty * 4 + 2) * HID + k];
        float4 a3 = *(const float4*)&sA[(ty * 4 + 3) * HID + k];
        float4 w0 = *(const float4*)&sW[(k + 0) * HID + tx * 4];
        float4 w1 = *(const float4*)&sW[(k + 1) * HID + tx * 4];
        float4 w2 = *(const float4*)&sW[(k + 2) * HID + tx * 4];
        float4 w3 = *(const float4*)&sW[(k + 3) * HID + tx * 4];
        mac4(a0.x, w0, acc[0]); mac4(a0.y, w1, acc[0]); mac4(a0.z, w2, acc[0]); mac4(a0.w, w3, acc[0]);
        mac4(a1.x, w0, acc[1]); mac4(a1.y, w1, acc[1]); mac4(a1.z, w2, acc[1]); mac4(a1.w, w3, acc[1]);
        mac4(a2.x, w0, acc[2]); mac4(a2.y, w1, acc[2]); mac4(a2.z, w2, acc[2]); mac4(a2.w, w3, acc[2]);
        mac4(a3.x, w0, acc[3]); mac4(a3.y, w1, acc[3]); mac4(a3.z, w2, acc[3]); mac4(a3.w, w3, acc[3]);
    }

    float4 bv = *(const float4*)&bias[tx * 4];
    int row0 = blockIdx.x * 32 + ty * 4;
#pragma unroll
    for (int r = 0; r < 4; ++r) {
        f16x4 o;
        o.x = (f16)fmaxf(acc[r][0] + bv.x, 0.0f);
        o.y = (f16)fmaxf(acc[r][1] + bv.y, 0.0f);
        o.z = (f16)fmaxf(acc[r][2] + bv.z, 0.0f);
        o.w = (f16)fmaxf(acc[r][3] + bv.w, 0.0f);
        *(f16x4*)&out[(size_t)(row0 + r) * HID + tx * 4] = o;
    }
}

// ---------------- pooling pass 1: per (graph, segment) partial sums, fp32, deterministic -----
__device__ __forceinline__ int lower_bound_batch(const int* __restrict__ batch, int val) {
    int lo = 0, hi = N_NODES;
    while (lo < hi) { int m = (lo + hi) >> 1; if (batch[m] < val) lo = m + 1; else hi = m; }
    return lo;
}

__global__ __launch_bounds__(128) void k_pool1(const f16* __restrict__ h, const int* __restrict__ batch,
                                               float* __restrict__ partials) {
    int g = blockIdx.x / POOL_SEG;
    int s = blockIdx.x % POOL_SEG;
    int f = threadIdx.x;
    int beg = lower_bound_batch(batch, g);
    int end = lower_bound_batch(batch, g + 1);
    int len = end - beg;
    int sb = beg + (int)(((long long)len * s) / POOL_SEG);
    int se = beg + (int)(((long long)len * (s + 1)) / POOL_SEG);
    float acc = 0.0f;
    for (int i = sb; i < se; ++i) acc += (float)h[i * HID + f];
    partials[(size_t)blockIdx.x * HID + f] = acc;
}

// ---------------- pooling pass 2 + head fused: pooled = sum/count; out = sigmoid(pooled@Wl+bl)
__global__ __launch_bounds__(128) void k_pool2h(const float* __restrict__ partials,
                                                const int* __restrict__ batch,
                                                const float* __restrict__ Wl, const float* __restrict__ bl,
                                                float* __restrict__ out) {
    __shared__ float sp[HID];
    int g = blockIdx.x;
    int f = threadIdx.x;
    float acc = 0.0f;
#pragma unroll
    for (int s = 0; s < POOL_SEG; ++s)
        acc += partials[(size_t)(g * POOL_SEG + s) * HID + f];
    int beg = lower_bound_batch(batch, g);
    int end = lower_bound_batch(batch, g + 1);
    sp[f] = acc / fmaxf((float)(end - beg), 1.0f);
    __syncthreads();
    if (f < N_CLS) {
        float v = bl[f];
        for (int k = 0; k < HID; ++k) v = fmaf(sp[k], Wl[k * N_CLS + f], v);
        out[g * N_CLS + f] = 1.0f / (1.0f + expf(-v));
    }
}

extern "C" void kernel_launch(void* const* d_in, const int* in_sizes, int n_in,
                              void* d_out, int out_size, void* d_ws, size_t ws_size,
                              hipStream_t stream) {
    const float* x     = (const float*)d_in[0];
    const int*   ei    = (const int*)d_in[1];
    const int*   batch = (const int*)d_in[2];
    const float* W1 = (const float*)d_in[3];  const float* b1 = (const float*)d_in[4];
    const float* W2 = (const float*)d_in[5];  const float* b2 = (const float*)d_in[6];
    const float* W3 = (const float*)d_in[7];  const float* b3 = (const float*)d_in[8];
    const float* W4 = (const float*)d_in[9];  const float* b4 = (const float*)d_in[10];
    const float* Wl = (const float*)d_in[11]; const float* bl = (const float*)d_in[12];
    float* out = (float*)d_out;

    char* p = (char*)d_ws;
    auto alloc = [&](size_t bytes) { char* r = p; p += (bytes + 255) & ~(size_t)255; return (void*)r; };
    int*   deg    = (int*)  alloc((size_t)N_NODES * 4);
    int*   rowptr = (int*)  alloc((size_t)(N_NODES + 1) * 4);
    int*   cursor = (int*)  alloc((size_t)N_NODES * 4);
    int*   bsum   = (int*)  alloc(512 * 4);
    float* dinv   = (float*)alloc((size_t)N_NODES * 4);
    int2*  edges  = (int2*) alloc((size_t)N_EDGES * 8);
    float* xagg   = (float*)alloc((size_t)N_NODES * F_IN * 4);
    f16*   h0     = (f16*)  alloc((size_t)N_NODES * HID * 2);
    f16*   h1     = (f16*)  alloc((size_t)N_NODES * HID * 2);
    float* parts  = (float*)alloc((size_t)N_GRAPH * POOL_SEG * HID * 4);

    const int* srcv = ei;              // edge_index[0]
    const int* dstv = ei + N_EDGES;    // edge_index[1]

    hipMemsetAsync(deg, 0, (size_t)N_NODES * 4, stream);
    hipMemsetAsync(cursor, 0, (size_t)N_NODES * 4, stream);

    const int nb = (N_NODES + 255) / 256;   // 391

    k_hist <<<N_EDGES / 256, 256, 0, stream>>>(dstv, deg);
    k_scan1<<<nb, 256, 0, stream>>>(deg, rowptr, bsum);
    k_scan2<<<1, 512, 0, stream>>>(bsum, nb);
    k_scan3<<<nb, 256, 0, stream>>>(rowptr, bsum);
    k_dinv <<<nb, 256, 0, stream>>>(deg, dinv);
    k_fill <<<N_EDGES / 256, 256, 0, stream>>>(srcv, dstv, rowptr, cursor, dinv, edges);

    // layer 1: Agg(x) @ W1  (aggregate the 4-wide features, then expand to 128)
    k_aggx <<<nb, 256, 0, stream>>>((const float4*)x, rowptr, edges, dinv, (float4*)xagg);
    k_gemm4<<<(N_NODES * 64) / 256, 256, 0, stream>>>((const float4*)xagg, W1, b1, (f16x2*)h0);

    // layers 2..4: Agg(h) @ W  (+bias, ReLU fused in GEMM epilogue)
    k_agg    <<<N_NODES / 4, 256, 0, stream>>>((const f16x2*)h0, rowptr, edges, dinv, (f16x2*)h1);
    k_gemm128<<<N_NODES / 32, 256, 0, stream>>>(h1, W2, b2, h0);
    k_agg    <<<N_NODES / 4, 256, 0, stream>>>((const f16x2*)h0, rowptr, edges, dinv, (f16x2*)h1);
    k_gemm128<<<N_NODES / 32, 256, 0, stream>>>(h1, W3, b3, h0);
    k_agg    <<<N_NODES / 4, 256, 0, stream>>>((const f16x2*)h0, rowptr, edges, dinv, (f16x2*)h1);
    k_gemm128<<<N_NODES / 32, 256, 0, stream>>>(h1, W4, b4, h0);

    k_pool1 <<<N_GRAPH * POOL_SEG, 128, 0, stream>>>(h0, batch, parts);
    k_pool2h<<<N_GRAPH, 128, 0, stream>>>(parts, batch, Wl, bl, out);
}

// Round 4
// 538.717 us; speedup vs baseline: 1.8297x; 1.2404x over previous
//
#include <hip/hip_runtime.h>
#include <math.h>

#define N_NODES 100000
#define N_EDGES 1600000
#define F_IN    4
#define HID     128
#define N_CLS   5
#define N_GRAPH 256
#define POOL_SEG 8

typedef _Float16 f16;
typedef _Float16 f16x2 __attribute__((ext_vector_type(2)));
typedef _Float16 f16x4 __attribute__((ext_vector_type(4)));
typedef _Float16 f16x8 __attribute__((ext_vector_type(8)));
typedef float f32x4 __attribute__((ext_vector_type(4)));

// ---------------- degree histogram over dst; atomic old value = edge rank within row --------
__global__ __launch_bounds__(256) void k_hist(const int* __restrict__ dst, int* __restrict__ deg,
                                              int* __restrict__ rank) {
    int e = blockIdx.x * 256 + threadIdx.x;
    if (e < N_EDGES) rank[e] = atomicAdd(&deg[dst[e]], 1);
}

// ---------------- exclusive scan (3-pass) ---------------
__global__ __launch_bounds__(256) void k_scan1(const int* __restrict__ cnt, int* __restrict__ excl,
                                               int* __restrict__ bsum) {
    __shared__ int s[256];
    int i = blockIdx.x * 256 + threadIdx.x;
    int v = (i < N_NODES) ? cnt[i] : 0;
    s[threadIdx.x] = v;
    __syncthreads();
    for (int off = 1; off < 256; off <<= 1) {
        int t = (threadIdx.x >= off) ? s[threadIdx.x - off] : 0;
        __syncthreads();
        s[threadIdx.x] += t;
        __syncthreads();
    }
    if (i < N_NODES) excl[i] = s[threadIdx.x] - v;
    if (threadIdx.x == 255) bsum[blockIdx.x] = s[255];
}

__global__ __launch_bounds__(512) void k_scan2(int* __restrict__ bsum, int nb) {
    __shared__ int s[512];
    int v = (threadIdx.x < nb) ? bsum[threadIdx.x] : 0;
    s[threadIdx.x] = v;
    __syncthreads();
    for (int off = 1; off < 512; off <<= 1) {
        int t = (threadIdx.x >= off) ? s[threadIdx.x - off] : 0;
        __syncthreads();
        s[threadIdx.x] += t;
        __syncthreads();
    }
    if (threadIdx.x < nb) bsum[threadIdx.x] = s[threadIdx.x] - v;
}

__global__ __launch_bounds__(256) void k_scan3(int* __restrict__ excl, const int* __restrict__ bsum) {
    int i = blockIdx.x * 256 + threadIdx.x;
    if (i < N_NODES) excl[i] += bsum[blockIdx.x];
    if (i == 0) excl[N_NODES] = N_EDGES;   // total in-degree (w/o self loops) is exactly E
}

// ---------------- dinv = (deg+1)^-0.5  (the +1 is the self loop) ---------------
__global__ __launch_bounds__(256) void k_dinv(const int* __restrict__ deg, float* __restrict__ dinv) {
    int i = blockIdx.x * 256 + threadIdx.x;
    if (i < N_NODES) dinv[i] = rsqrtf((float)deg[i] + 1.0f);
}

// ---------------- CSR fill: no atomics (rank precomputed); one 8B scattered write per edge ---
__global__ __launch_bounds__(256) void k_fill(const int* __restrict__ src, const int* __restrict__ dst,
                                              const int* __restrict__ rank,
                                              const int* __restrict__ rowptr,
                                              const float* __restrict__ dinv,
                                              int2* __restrict__ edges) {
    int e = blockIdx.x * 256 + threadIdx.x;
    if (e < N_EDGES) {
        int d = dst[e], s = src[e];
        int ppos = rowptr[d] + rank[e];
        float c = dinv[s] * dinv[d];
        edges[ppos] = make_int2(s, __float_as_int(c));
    }
}

// ---------------- aggregate raw features x (N x 4) — Agg(x) before the layer-1 GEMM ----------
__global__ __launch_bounds__(256) void k_aggx(const float4* __restrict__ x, const int* __restrict__ rowptr,
                                              const int2* __restrict__ edges,
                                              const float* __restrict__ dinv, float4* __restrict__ out) {
    int i = blockIdx.x * 256 + threadIdx.x;
    if (i >= N_NODES) return;
    float di = dinv[i];
    float4 xv = x[i];
    float c0 = di * di;
    float ax = c0 * xv.x, ay = c0 * xv.y, az = c0 * xv.z, aw = c0 * xv.w;
    int beg = rowptr[i], end = rowptr[i + 1];
    for (int e = beg; e < end; ++e) {
        int2 m = edges[e];
        float c = __int_as_float(m.y);
        float4 v = x[m.x];
        ax = fmaf(c, v.x, ax); ay = fmaf(c, v.y, ay);
        az = fmaf(c, v.z, az); aw = fmaf(c, v.w, aw);
    }
    out[i] = make_float4(ax, ay, az, aw);
}

// ---------------- layer-1 GEMM: (N x 4) @ (4 x 128) + bias, ReLU, fp16 out ---------------
__global__ __launch_bounds__(256) void k_gemm4(const float4* __restrict__ A, const float* __restrict__ W,
                                               const float* __restrict__ bias, f16x2* __restrict__ out) {
    int idx = blockIdx.x * 256 + threadIdx.x;      // idx = i*64 + fpair
    int i = idx >> 6, fp = (idx & 63) * 2;
    float4 a = A[i];
    float v0 = bias[fp];
    v0 = fmaf(a.x, W[fp],           v0);
    v0 = fmaf(a.y, W[HID + fp],     v0);
    v0 = fmaf(a.z, W[2 * HID + fp], v0);
    v0 = fmaf(a.w, W[3 * HID + fp], v0);
    float v1 = bias[fp + 1];
    v1 = fmaf(a.x, W[fp + 1],           v1);
    v1 = fmaf(a.y, W[HID + fp + 1],     v1);
    v1 = fmaf(a.z, W[2 * HID + fp + 1], v1);
    v1 = fmaf(a.w, W[3 * HID + fp + 1], v1);
    f16x2 o;
    o.x = (f16)fmaxf(v0, 0.0f);
    o.y = (f16)fmaxf(v1, 0.0f);
    out[idx] = o;
}

// ---------------- CSR aggregation, fp16 payload: one wave per node, half2 per lane -----------
__global__ __launch_bounds__(256) void k_agg(const f16x2* __restrict__ h, const int* __restrict__ rowptr,
                                             const int2* __restrict__ edges,
                                             const float* __restrict__ dinv, f16x2* __restrict__ out) {
    int node = blockIdx.x * 4 + (threadIdx.x >> 6);
    if (node >= N_NODES) return;
    int lane = threadIdx.x & 63;
    int beg = rowptr[node], end = rowptr[node + 1];
    float di = dinv[node];
    f16x2 self = h[node * 64 + lane];
    float c0 = di * di;
    float accx = c0 * (float)self.x;
    float accy = c0 * (float)self.y;
    int e = beg;
    for (; e + 8 <= end; e += 8) {
        int2 m0 = edges[e + 0], m1 = edges[e + 1], m2 = edges[e + 2], m3 = edges[e + 3];
        int2 m4 = edges[e + 4], m5 = edges[e + 5], m6 = edges[e + 6], m7 = edges[e + 7];
        f16x2 v0 = h[m0.x * 64 + lane], v1 = h[m1.x * 64 + lane];
        f16x2 v2 = h[m2.x * 64 + lane], v3 = h[m3.x * 64 + lane];
        f16x2 v4 = h[m4.x * 64 + lane], v5 = h[m5.x * 64 + lane];
        f16x2 v6 = h[m6.x * 64 + lane], v7 = h[m7.x * 64 + lane];
        accx = fmaf(__int_as_float(m0.y), (float)v0.x, accx);
        accy = fmaf(__int_as_float(m0.y), (float)v0.y, accy);
        accx = fmaf(__int_as_float(m1.y), (float)v1.x, accx);
        accy = fmaf(__int_as_float(m1.y), (float)v1.y, accy);
        accx = fmaf(__int_as_float(m2.y), (float)v2.x, accx);
        accy = fmaf(__int_as_float(m2.y), (float)v2.y, accy);
        accx = fmaf(__int_as_float(m3.y), (float)v3.x, accx);
        accy = fmaf(__int_as_float(m3.y), (float)v3.y, accy);
        accx = fmaf(__int_as_float(m4.y), (float)v4.x, accx);
        accy = fmaf(__int_as_float(m4.y), (float)v4.y, accy);
        accx = fmaf(__int_as_float(m5.y), (float)v5.x, accx);
        accy = fmaf(__int_as_float(m5.y), (float)v5.y, accy);
        accx = fmaf(__int_as_float(m6.y), (float)v6.x, accx);
        accy = fmaf(__int_as_float(m6.y), (float)v6.y, accy);
        accx = fmaf(__int_as_float(m7.y), (float)v7.x, accx);
        accy = fmaf(__int_as_float(m7.y), (float)v7.y, accy);
    }
    for (; e < end; ++e) {
        int2 m = edges[e];
        f16x2 v = h[m.x * 64 + lane];
        float c = __int_as_float(m.y);
        accx = fmaf(c, (float)v.x, accx);
        accy = fmaf(c, (float)v.y, accy);
    }
    f16x2 o;
    o.x = (f16)accx;
    o.y = (f16)accy;
    out[node * 64 + lane] = o;
}

// ---------------- pack W (128x128 fp32) into MFMA B-fragment order, fp16 ---------------
// Wp[((ct*4 + ks)*64 + lane)*8 + j] = W[ks*32 + (lane>>4)*8 + j][ct*16 + (lane&15)]
__global__ __launch_bounds__(256) void k_packW(const float* __restrict__ W, f16* __restrict__ Wp) {
    int idx = blockIdx.x * 256 + threadIdx.x;   // 64 blocks x 256 = 16384
    int j  = idx & 7;
    int L  = (idx >> 3) & 63;
    int ks = (idx >> 9) & 3;
    int ct = idx >> 11;
    int k = ks * 32 + (L >> 4) * 8 + j;
    int n = ct * 16 + (L & 15);
    Wp[idx] = (f16)W[k * HID + n];
}

// ---------------- main GEMM via MFMA: (N x 128 f16) @ Wp + bias, ReLU, f16 out ---------------
// Wave handles 16 rows x 128 cols. A-frag: lane holds A[row0 + (lane&15)][ks*32 + (lane>>4)*8 + j].
// C/D: col = lane&15 (+16*tile), row = (lane>>4)*4 + reg.
__global__ __launch_bounds__(256) void k_gemm_mfma(const f16* __restrict__ A, const f16* __restrict__ Wp,
                                                   const float* __restrict__ bias, f16* __restrict__ out) {
    int wave = threadIdx.x >> 6;
    int lane = threadIdx.x & 63;
    int row0 = blockIdx.x * 64 + wave * 16;
    if (row0 >= N_NODES) return;
    int m = lane & 15;
    int q = lane >> 4;
    const f16* Arow = A + (size_t)(row0 + m) * HID + q * 8;

    f32x4 acc[8];
#pragma unroll
    for (int t = 0; t < 8; ++t) acc[t] = (f32x4){0.f, 0.f, 0.f, 0.f};

#pragma unroll
    for (int ks = 0; ks < 4; ++ks) {
        f16x8 a = *(const f16x8*)(Arow + ks * 32);
#pragma unroll
        for (int t = 0; t < 8; ++t) {
            f16x8 b = *(const f16x8*)(Wp + ((size_t)(t * 4 + ks) * 64 + lane) * 8);
            acc[t] = __builtin_amdgcn_mfma_f32_16x16x32_f16(a, b, acc[t], 0, 0, 0);
        }
    }

    int orow = row0 + q * 4;
#pragma unroll
    for (int t = 0; t < 8; ++t) {
        float bb = bias[t * 16 + m];
#pragma unroll
        for (int r = 0; r < 4; ++r) {
            out[(size_t)(orow + r) * HID + t * 16 + m] = (f16)fmaxf(acc[t][r] + bb, 0.0f);
        }
    }
}

// ---------------- pooling pass 1: per (graph, segment) partial sums, fp32, deterministic -----
__device__ __forceinline__ int lower_bound_batch(const int* __restrict__ batch, int val) {
    int lo = 0, hi = N_NODES;
    while (lo < hi) { int m = (lo + hi) >> 1; if (batch[m] < val) lo = m + 1; else hi = m; }
    return lo;
}

__global__ __launch_bounds__(128) void k_pool1(const f16* __restrict__ h, const int* __restrict__ batch,
                                               float* __restrict__ partials) {
    int g = blockIdx.x / POOL_SEG;
    int s = blockIdx.x % POOL_SEG;
    int f = threadIdx.x;
    int beg = lower_bound_batch(batch, g);
    int end = lower_bound_batch(batch, g + 1);
    int len = end - beg;
    int sb = beg + (int)(((long long)len * s) / POOL_SEG);
    int se = beg + (int)(((long long)len * (s + 1)) / POOL_SEG);
    float acc = 0.0f;
    for (int i = sb; i < se; ++i) acc += (float)h[i * HID + f];
    partials[(size_t)blockIdx.x * HID + f] = acc;
}

// ---------------- pooling pass 2 + head fused: pooled = sum/count; out = sigmoid(pooled@Wl+bl)
__global__ __launch_bounds__(128) void k_pool2h(const float* __restrict__ partials,
                                                const int* __restrict__ batch,
                                                const float* __restrict__ Wl, const float* __restrict__ bl,
                                                float* __restrict__ out) {
    __shared__ float sp[HID];
    int g = blockIdx.x;
    int f = threadIdx.x;
    float acc = 0.0f;
#pragma unroll
    for (int s = 0; s < POOL_SEG; ++s)
        acc += partials[(size_t)(g * POOL_SEG + s) * HID + f];
    int beg = lower_bound_batch(batch, g);
    int end = lower_bound_batch(batch, g + 1);
    sp[f] = acc / fmaxf((float)(end - beg), 1.0f);
    __syncthreads();
    if (f < N_CLS) {
        float v = bl[f];
        for (int k = 0; k < HID; ++k) v = fmaf(sp[k], Wl[k * N_CLS + f], v);
        out[g * N_CLS + f] = 1.0f / (1.0f + expf(-v));
    }
}

extern "C" void kernel_launch(void* const* d_in, const int* in_sizes, int n_in,
                              void* d_out, int out_size, void* d_ws, size_t ws_size,
                              hipStream_t stream) {
    const float* x     = (const float*)d_in[0];
    const int*   ei    = (const int*)d_in[1];
    const int*   batch = (const int*)d_in[2];
    const float* W1 = (const float*)d_in[3];  const float* b1 = (const float*)d_in[4];
    const float* W2 = (const float*)d_in[5];  const float* b2 = (const float*)d_in[6];
    const float* W3 = (const float*)d_in[7];  const float* b3 = (const float*)d_in[8];
    const float* W4 = (const float*)d_in[9];  const float* b4 = (const float*)d_in[10];
    const float* Wl = (const float*)d_in[11]; const float* bl = (const float*)d_in[12];
    float* out = (float*)d_out;

    char* p = (char*)d_ws;
    auto alloc = [&](size_t bytes) { char* r = p; p += (bytes + 255) & ~(size_t)255; return (void*)r; };
    int*   deg    = (int*)  alloc((size_t)N_NODES * 4);
    int*   rowptr = (int*)  alloc((size_t)(N_NODES + 1) * 4);
    int*   rank   = (int*)  alloc((size_t)N_EDGES * 4);
    int*   bsum   = (int*)  alloc(512 * 4);
    float* dinv   = (float*)alloc((size_t)N_NODES * 4);
    int2*  edges  = (int2*) alloc((size_t)N_EDGES * 8);
    float* xagg   = (float*)alloc((size_t)N_NODES * F_IN * 4);
    f16*   h0     = (f16*)  alloc((size_t)N_NODES * HID * 2);
    f16*   h1     = (f16*)  alloc((size_t)N_NODES * HID * 2);
    float* parts  = (float*)alloc((size_t)N_GRAPH * POOL_SEG * HID * 4);
    f16*   Wp2    = (f16*)  alloc((size_t)HID * HID * 2);
    f16*   Wp3    = (f16*)  alloc((size_t)HID * HID * 2);
    f16*   Wp4    = (f16*)  alloc((size_t)HID * HID * 2);

    const int* srcv = ei;              // edge_index[0]
    const int* dstv = ei + N_EDGES;    // edge_index[1]

    hipMemsetAsync(deg, 0, (size_t)N_NODES * 4, stream);

    const int nb = (N_NODES + 255) / 256;   // 391

    k_hist <<<N_EDGES / 256, 256, 0, stream>>>(dstv, deg, rank);
    k_scan1<<<nb, 256, 0, stream>>>(deg, rowptr, bsum);
    k_scan2<<<1, 512, 0, stream>>>(bsum, nb);
    k_scan3<<<nb, 256, 0, stream>>>(rowptr, bsum);
    k_dinv <<<nb, 256, 0, stream>>>(deg, dinv);
    k_fill <<<N_EDGES / 256, 256, 0, stream>>>(srcv, dstv, rank, rowptr, dinv, edges);

    // pack the three 128x128 weights into MFMA B-fragment order (fp16)
    k_packW<<<64, 256, 0, stream>>>(W2, Wp2);
    k_packW<<<64, 256, 0, stream>>>(W3, Wp3);
    k_packW<<<64, 256, 0, stream>>>(W4, Wp4);

    // layer 1: Agg(x) @ W1  (aggregate the 4-wide features, then expand to 128)
    k_aggx <<<nb, 256, 0, stream>>>((const float4*)x, rowptr, edges, dinv, (float4*)xagg);
    k_gemm4<<<(N_NODES * 64) / 256, 256, 0, stream>>>((const float4*)xagg, W1, b1, (f16x2*)h0);

    // layers 2..4: Agg(h) @ W  (+bias, ReLU fused in GEMM epilogue), MFMA GEMMs
    const int gemm_grid = (N_NODES + 63) / 64;   // 1563
    k_agg      <<<N_NODES / 4, 256, 0, stream>>>((const f16x2*)h0, rowptr, edges, dinv, (f16x2*)h1);
    k_gemm_mfma<<<gemm_grid, 256, 0, stream>>>(h1, Wp2, b2, h0);
    k_agg      <<<N_NODES / 4, 256, 0, stream>>>((const f16x2*)h0, rowptr, edges, dinv, (f16x2*)h1);
    k_gemm_mfma<<<gemm_grid, 256, 0, stream>>>(h1, Wp3, b3, h0);
    k_agg      <<<N_NODES / 4, 256, 0, stream>>>((const f16x2*)h0, rowptr, edges, dinv, (f16x2*)h1);
    k_gemm_mfma<<<gemm_grid, 256, 0, stream>>>(h1, Wp4, b4, h0);

    k_pool1 <<<N_GRAPH * POOL_SEG, 128, 0, stream>>>(h0, batch, parts);
    k_pool2h<<<N_GRAPH, 128, 0, stream>>>(parts, batch, Wl, bl, out);
}